// Round 9
// baseline (1810.049 us; speedup 1.0000x reference)
//
#include <hip/hip_runtime.h>
#include <cstdint>
#include <cstddef>
#include <cmath>

#define DI __device__ __forceinline__

constexpr int B_ = 8;
constexpr int F0_ = 64;
constexpr int LAT_ = 512;
constexpr int P_ = 45376;
constexpr int NLAY_ = 16;

typedef __attribute__((ext_vector_type(8))) short short8;
typedef __attribute__((ext_vector_type(4))) float f32x4;

// wpk per-(c,b) slot (bf16): W1A(0.6*W1)[128][192] | W1B(0.4*W1)[128][192] |
//                            WS[128][192] | W2(0.1*)[128][128]
constexpr int WPK_STRIDE = 90112;
constexpr int WPK_W1B = 24576;
constexpr int WPK_WS  = 49152;
constexpr int WPK_W2  = 73728;

// ---- workspace layout (float offsets). out buffers PX-MAJOR: out[b][px][64ch]
constexpr size_t OFF_PART   = 0;          // 8*32*384 = 98304
constexpr size_t OFF_B3     = 98304;      // 40960
constexpr size_t OFF_LATCBF = 139264;     // 32768
constexpr size_t OFF_OUT0   = 172032;     // 8388608
constexpr size_t OFF_OUT1   = 8560640;    // 8388608
constexpr size_t OFF_WPK    = 16949248;   // 128*90112 u16 = 5767168 f -> end ~90.9 MB

DI uint16_t f2bf(float f) {
  uint32_t u = __float_as_uint(f);
  uint32_t r = (u + 0x7FFFu + ((u >> 16) & 1u)) >> 16;
  return (uint16_t)r;
}
DI uint32_t pk2bf(float a, float b) {
  return (uint32_t)f2bf(a) | ((uint32_t)f2bf(b) << 16);
}

// ---------------- threefry2x32 ----------------
DI void tf_cipher(uint32_t k0, uint32_t k1, uint32_t x0, uint32_t x1,
                  uint32_t& o0, uint32_t& o1) {
  const uint32_t ks2 = k0 ^ k1 ^ 0x1BD11BDAu;
  uint32_t a = x0 + k0, b = x1 + k1;
#define TFR(r) { a += b; b = (b << (r)) | (b >> (32 - (r))); b ^= a; }
  TFR(13) TFR(15) TFR(26) TFR(6)  a += k1;  b += ks2 + 1u;
  TFR(17) TFR(29) TFR(16) TFR(24) a += ks2; b += k0 + 2u;
  TFR(13) TFR(15) TFR(26) TFR(6)  a += k0;  b += k1 + 3u;
  TFR(17) TFR(29) TFR(16) TFR(24) a += k1;  b += ks2 + 4u;
  TFR(13) TFR(15) TFR(26) TFR(6)  a += ks2; b += k0 + 5u;
#undef TFR
  o0 = a; o1 = b;
}

static void host_tf_cipher(uint32_t k0, uint32_t k1, uint32_t x0, uint32_t x1,
                           uint32_t& o0, uint32_t& o1) {
  const uint32_t ks2 = k0 ^ k1 ^ 0x1BD11BDAu;
  uint32_t a = x0 + k0, b = x1 + k1;
#define TFR(r) { a += b; b = (b << (r)) | (b >> (32 - (r))); b ^= a; }
  TFR(13) TFR(15) TFR(26) TFR(6)  a += k1;  b += ks2 + 1u;
  TFR(17) TFR(29) TFR(16) TFR(24) a += ks2; b += k0 + 2u;
  TFR(13) TFR(15) TFR(26) TFR(6)  a += k0;  b += k1 + 3u;
  TFR(17) TFR(29) TFR(16) TFR(24) a += k1;  b += ks2 + 4u;
  TFR(13) TFR(15) TFR(26) TFR(6)  a += ks2; b += k0 + 5u;
#undef TFR
  o0 = a; o1 = b;
}

DI float erfinv_f(float x) {
  float w = -log1pf(-x * x);
  float p;
  if (w < 5.0f) {
    w = w - 2.5f;
    p = 2.81022636e-08f;
    p = fmaf(p, w, 3.43273939e-07f);
    p = fmaf(p, w, -3.5233877e-06f);
    p = fmaf(p, w, -4.39150654e-06f);
    p = fmaf(p, w, 0.00021858087f);
    p = fmaf(p, w, -0.00125372503f);
    p = fmaf(p, w, -0.00417768164f);
    p = fmaf(p, w, 0.246640727f);
    p = fmaf(p, w, 1.50140941f);
  } else {
    w = sqrtf(w) - 3.0f;
    p = -0.000200214257f;
    p = fmaf(p, w, 0.000100950558f);
    p = fmaf(p, w, 0.00134934322f);
    p = fmaf(p, w, -0.00367342844f);
    p = fmaf(p, w, 0.00573950773f);
    p = fmaf(p, w, -0.0076224613f);
    p = fmaf(p, w, 0.00943887047f);
    p = fmaf(p, w, 1.00167406f);
    p = fmaf(p, w, 2.83297682f);
  }
  return p * x;
}

DI float noise_val(uint32_t k0, uint32_t k1, uint32_t idx) {
  uint32_t o0, o1;
  tf_cipher(k0, k1, 0u, idx, o0, o1);
  uint32_t bits = o0 ^ o1;
  float f = __uint_as_float((bits >> 9) | 0x3f800000u) - 1.0f;
  const float lo = -0.99999994f;
  float u = fmaxf(lo, fmaf(f, 2.0f, lo));
  return 1.41421354f * erfinv_f(u);
}

// ---------------- seed broadcast ----------------
__global__ __launch_bounds__(256) void k_seed(const float* __restrict__ seed,
                                              float* __restrict__ outb) {
  const int idx = blockIdx.x * 256 + threadIdx.x;
  const int px = (idx >> 6) & 255, ch = idx & 63;
  outb[idx] = seed[ch * 256 + px];
}

// ---------------- latc (bf16) ----------------
__global__ __launch_bounds__(256) void k_latc(const float* __restrict__ lat,
                                              const float* __restrict__ wexp,
                                              const float* __restrict__ bexp,
                                              unsigned short* __restrict__ latc_bf) {
  const int c = blockIdx.x;
  const int tid = threadIdx.x;
  __shared__ float latS[B_][LAT_];
  for (int i = tid; i < B_ * LAT_; i += 256) latS[i >> 9][i & 511] = lat[i];
  __syncthreads();
  for (int o = tid; o < LAT_; o += 256) {
    float acc[B_] = {0, 0, 0, 0, 0, 0, 0, 0};
    const float* wr = wexp + ((size_t)c * LAT_ + o) * LAT_;
    for (int k = 0; k < LAT_; k += 4) {
      float4 w4 = *(const float4*)(wr + k);
#pragma unroll
      for (int b = 0; b < B_; ++b) {
        acc[b] = fmaf(w4.x, latS[b][k + 0], acc[b]);
        acc[b] = fmaf(w4.y, latS[b][k + 1], acc[b]);
        acc[b] = fmaf(w4.z, latS[b][k + 2], acc[b]);
        acc[b] = fmaf(w4.w, latS[b][k + 3], acc[b]);
      }
    }
    const float bb = bexp[c * LAT_ + o];
#pragma unroll
    for (int b = 0; b < B_; ++b)
      latc_bf[((size_t)c * B_ + b) * LAT_ + o] = f2bf(acc[b] + bb);
  }
}

// ---------------- static weight fill ----------------
__global__ __launch_bounds__(256) void k_wstatic(const float* __restrict__ conv0_w,
                                                 const float* __restrict__ conv1_w,
                                                 unsigned short* __restrict__ wpk) {
  const int cb = blockIdx.x;
  unsigned short* wq = wpk + (size_t)cb * WPK_STRIDE;
  for (int i = threadIdx.x; i < 64 * 192; i += 256) {
    const float v = conv0_w[i];
    wq[i] = f2bf(0.6f * v);
    wq[WPK_W1B + i] = f2bf(0.4f * v);
  }
  for (int i = threadIdx.x; i < 128 * 64; i += 256) {
    int oc = i >> 6, k = i & 63;
    wq[WPK_W2 + oc * 128 + k] = f2bf(0.1f * conv1_w[i]);
  }
}

// ---------------- ks via bf16 MFMA ----------------
__global__ __launch_bounds__(256) void k_ks(
    const unsigned short* __restrict__ latc_bf,
    const float* __restrict__ dyna_w,
    const float* __restrict__ dyna_b,
    const float* __restrict__ convs_w,
    unsigned short* __restrict__ wpk,
    float* __restrict__ bias3) {
  const int n0 = blockIdx.x * 64;
  const int tid = threadIdx.x;
  const int wv = tid >> 6, lane = tid & 63, lg = lane >> 4, lr = lane & 15;
  __shared__ __align__(16) unsigned char AsB[128 * 64];
  __shared__ __align__(16) unsigned char BsB[64 * 64];

  f32x4 acc[2][4];
#pragma unroll
  for (int i = 0; i < 2; ++i)
#pragma unroll
    for (int j = 0; j < 4; ++j) acc[i][j] = (f32x4)0.f;

  const int am = tid >> 1, ah = tid & 1;
  const int bn = tid >> 2, bq = tid & 3;

  for (int kc = 0; kc < LAT_; kc += 32) {
    __syncthreads();
    {
      const uint4* src = (const uint4*)(latc_bf + (size_t)am * LAT_ + kc + ah * 16);
      const uint4 u0 = src[0];
      const uint4 u1 = src[1];
      const int swz = (am & 7) << 4;
      *(uint4*)(AsB + ((am * 64 + ah * 32) ^ swz)) = u0;
      *(uint4*)(AsB + ((am * 64 + ah * 32 + 16) ^ swz)) = u1;
    }
    {
      const float* src = dyna_w + (size_t)(n0 + bn) * LAT_ + kc + bq * 8;
      const float4 f0 = *(const float4*)(src);
      const float4 f1 = *(const float4*)(src + 4);
      uint4 u;
      u.x = pk2bf(f0.x, f0.y);
      u.y = pk2bf(f0.z, f0.w);
      u.z = pk2bf(f1.x, f1.y);
      u.w = pk2bf(f1.z, f1.w);
      *(uint4*)(BsB + ((bn * 64 + bq * 16) ^ ((bn & 7) << 4))) = u;
    }
    __syncthreads();
    short8 af[2], bfx[4];
#pragma unroll
    for (int mt = 0; mt < 2; ++mt) {
      const int rm = wv * 32 + mt * 16 + lr;
      af[mt] = *(const short8*)(AsB + ((rm * 64 + lg * 16) ^ ((rm & 7) << 4)));
    }
#pragma unroll
    for (int nt = 0; nt < 4; ++nt) {
      const int rn = nt * 16 + lr;
      bfx[nt] = *(const short8*)(BsB + ((rn * 64 + lg * 16) ^ ((rn & 7) << 4)));
    }
#pragma unroll
    for (int mt = 0; mt < 2; ++mt)
#pragma unroll
      for (int nt = 0; nt < 4; ++nt)
        acc[mt][nt] = __builtin_amdgcn_mfma_f32_16x16x32_bf16(af[mt], bfx[nt], acc[mt][nt], 0, 0, 0);
  }

#pragma unroll
  for (int nt = 0; nt < 4; ++nt) {
    const int n = n0 + nt * 16 + lr;
    int typ, e_off;
    float addv = 0.f;
    if (n < 12288) { int oc = n / 192; int k = n - oc * 192; typ = 0; e_off = (64 + oc) * 192 + k; }
    else if (n < 12352) { typ = 1; e_off = n - 12288; }
    else if (n < 20544) { int m2 = n - 12352; typ = 2; e_off = WPK_W2 + (m2 >> 6) * 128 + 64 + (m2 & 63); }
    else if (n < 20672) { typ = 3; e_off = 64 + (n - 20544); }
    else if (n < 45248) {
      int m3 = n - 20672; int oc = m3 / 192; int k = m3 - oc * 192;
      typ = 4; e_off = WPK_WS + oc * 192 + k; addv = convs_w[oc * 192 + k];
    } else { typ = 5; e_off = 192 + (n - 45248); }
    const float db = dyna_b[n];
#pragma unroll
    for (int mt = 0; mt < 2; ++mt) {
#pragma unroll
      for (int reg = 0; reg < 4; ++reg) {
        const int cb = wv * 32 + mt * 16 + lg * 4 + reg;
        float v = acc[mt][nt][reg] + db;
        if (typ == 4) v += addv;
        if (typ == 2) v *= 0.1f;
        if (typ == 0) {
          wpk[(size_t)cb * WPK_STRIDE + e_off] = f2bf(0.6f * v);
          wpk[(size_t)cb * WPK_STRIDE + WPK_W1B + e_off] = f2bf(0.4f * v);
        } else if (typ == 2 || typ == 4) {
          wpk[(size_t)cb * WPK_STRIDE + e_off] = f2bf(v);
        } else {
          bias3[(size_t)cb * 320 + e_off] = v;
        }
      }
    }
  }
}

DI f32x4 ldc(const float* p, bool c) { return c ? *(const f32x4*)p : (f32x4)0.f; }

// ---------------- stats pass (px-major, NS strip partials) ----------------
__global__ __launch_bounds__(256) void k_stats1(const float* __restrict__ cur,
                                                float* __restrict__ part,
                                                int H, int W, int logW, int HW,
                                                int NS) {
  const int b = blockIdx.y;
  const int strip = blockIdx.x;
  const int tid = threadIdx.x;
  const int chq = tid & 15, pxo = (tid >> 4) & 3, wv = tid >> 6;
  const int pxs = HW / NS;
  const int p0 = strip * pxs;
  const float* __restrict__ ob = cur + (size_t)b * HW * 64 + chq * 4;

  f32x4 s[6];
#pragma unroll
  for (int i = 0; i < 6; ++i) s[i] = (f32x4)0.f;

  for (int px = p0 + (wv * 4 + pxo); px < p0 + pxs; px += 16) {
    const int h = px >> logW, w = px & (W - 1);
    const bool vu = h > 0, vd = h < H - 1, vl = w > 0, vr = w < W - 1;
    const float* bp = ob + (size_t)px * 64;
    const int rW = W * 64;
    const f32x4 c11 = *(const f32x4*)(bp);
    f32x4 vx = ldc(bp - rW + 64, vu && vr) - ldc(bp - rW - 64, vu && vl)
             + 2.f * (ldc(bp + 64, vr) - ldc(bp - 64, vl))
             + ldc(bp + rW + 64, vd && vr) - ldc(bp + rW - 64, vd && vl);
    f32x4 vy = ldc(bp + rW - 64, vd && vl) + 2.f * ldc(bp + rW, vd) + ldc(bp + rW + 64, vd && vr)
             - ldc(bp - rW - 64, vu && vl) - 2.f * ldc(bp - rW, vu) - ldc(bp - rW + 64, vu && vr);
    vx *= 0.125f; vy *= 0.125f;
    s[0] += vx; s[1] += vx * vx;
    s[2] += vy; s[3] += vy * vy;
    s[4] += c11; s[5] += c11 * c11;
  }
#pragma unroll
  for (int i = 0; i < 6; ++i)
#pragma unroll
    for (int c = 0; c < 4; ++c) {
      s[i][c] += __shfl_xor(s[i][c], 16, 64);
      s[i][c] += __shfl_xor(s[i][c], 32, 64);
    }
  __shared__ f32x4 redS[64][6];
  if ((tid & 63) < 16) {
#pragma unroll
    for (int i = 0; i < 6; ++i) redS[wv * 16 + chq][i] = s[i];
  }
  __syncthreads();
  if (tid < 16) {
    f32x4 a[6];
#pragma unroll
    for (int i = 0; i < 6; ++i)
      a[i] = redS[tid][i] + redS[16 + tid][i] + redS[32 + tid][i] + redS[48 + tid][i];
    float* pp = part + (size_t)(b * NS + strip) * 384;
#pragma unroll
    for (int i = 0; i < 6; ++i) {
      const int sec = i >> 1, wbit = i & 1;
#pragma unroll
      for (int c = 0; c < 4; ++c)
        pp[sec * 128 + wbit * 64 + tid * 4 + c] = a[i][c];
    }
  }
}

// ---------------- fused main layer: wave-decoupled, register-resident p ----------------
__global__ __launch_bounds__(256, 4) void k_main(
    const float* __restrict__ cur, float* __restrict__ nxt,
    const float* __restrict__ part,
    const unsigned short* __restrict__ wpk_layer,
    const float* __restrict__ bias3_layer,
    const float* __restrict__ conv0_b,
    const float* __restrict__ conv1_b,
    const float* __restrict__ noise_w_c,
    const float* __restrict__ leak_ptr,
    int HW, int W, int lwpr, int NS, unsigned key0, unsigned key1) {
  const int b = blockIdx.y;
  const int bx = blockIdx.x;
  const int tr = bx >> lwpr, tc = bx & ((1 << lwpr) - 1);
  const int r0 = tr * 4, c0 = tc * 16;
  const int logW = lwpr + 4;
  const int H = HW >> logW;

  const int tid = threadIdx.x;
  const int wv = tid >> 6, lane = tid & 63;
  const int lg = lane >> 4, lr = lane & 15;

  __shared__ float mrS[384];
  __shared__ __align__(16) unsigned short HsAll[4][16 * 138];  // 17.7KB, wave-private rows

  const unsigned short* wq = wpk_layer + (size_t)b * WPK_STRIDE;
  const unsigned short* W1A = wq;
  const unsigned short* W1B = wq + WPK_W1B;
  const unsigned short* WS  = wq + WPK_WS;
  const unsigned short* W2  = wq + WPK_W2;
  const float* b3 = bias3_layer + (size_t)b * 320;

  // --- prologue (only block-wide phase): merge strip partials -> mrS
  if (tid < 192) {
    const int sec = tid >> 6, ch = tid & 63;
    const float* pb = part + (size_t)b * NS * 384;
    float s1 = 0.f, s2 = 0.f;
    for (int st = 0; st < NS; ++st) {
      s1 += pb[st * 384 + sec * 128 + ch];
      s2 += pb[st * 384 + sec * 128 + 64 + ch];
    }
    const float inv = 1.0f / (float)HW;
    const float m = s1 * inv;
    mrS[sec * 64 + ch] = m;
    mrS[192 + sec * 64 + ch] = rsqrtf(fmaxf(s2 * inv - m * m, 0.f) + 1e-5f);
  }
  __syncthreads();

  // --- per-wave geometry: wave owns row gr = r0+wv, 16 px (cols c0..c0+15)
  const int gr = r0 + wv;
  const int gc = c0 + lr;
  const bool vu = gr > 0, vd = gr < H - 1, vl = gc > 0, vr = gc < W - 1;
  const float* rowb = cur + ((size_t)b * HW + (size_t)gr * W + gc) * 64;
  const int rW = W * 64;
  const float nzv = noise_val(key0, key1, (unsigned)(b * HW + gr * W + gc));

  f32x4 accH[8], accO[8];
#pragma unroll
  for (int g = 0; g < 8; ++g) { accH[g] = (f32x4)0.f; accO[g] = (f32x4)0.f; }

  // --- GEMM1 + GEMM2A: per kc, build p fragment in registers then 24 MFMAs
#pragma unroll
  for (int kc = 0; kc < 6; ++kc) {
    const int ch0 = kc * 32 + lg * 8;   // p-channel strip (also the weight k index)
    const int t = ch0 >> 6;             // 0=vx, 1=vy, 2=vi
    const int oc8 = ch0 & 63;           // out-channel strip base
    const float* bq = rowb + oc8;
    f32x4 n0, n1;
    if (t == 2) {
      n0 = *(const f32x4*)(bq);
      n1 = *(const f32x4*)(bq + 4);
    } else if (t == 0) {
      n0 = ldc(bq - rW + 64, vu && vr) - ldc(bq - rW - 64, vu && vl)
         + 2.f * (ldc(bq + 64, vr) - ldc(bq - 64, vl))
         + ldc(bq + rW + 64, vd && vr) - ldc(bq + rW - 64, vd && vl);
      n1 = ldc(bq - rW + 68, vu && vr) - ldc(bq - rW - 60, vu && vl)
         + 2.f * (ldc(bq + 68, vr) - ldc(bq - 60, vl))
         + ldc(bq + rW + 68, vd && vr) - ldc(bq + rW - 60, vd && vl);
      n0 *= 0.125f; n1 *= 0.125f;
    } else {
      n0 = ldc(bq + rW - 64, vd && vl) + 2.f * ldc(bq + rW, vd) + ldc(bq + rW + 64, vd && vr)
         - ldc(bq - rW - 64, vu && vl) - 2.f * ldc(bq - rW, vu) - ldc(bq - rW + 64, vu && vr);
      n1 = ldc(bq + rW - 60, vd && vl) + 2.f * ldc(bq + rW + 4, vd) + ldc(bq + rW + 68, vd && vr)
         - ldc(bq - rW - 60, vu && vl) - 2.f * ldc(bq - rW + 4, vu) - ldc(bq - rW + 68, vu && vr);
      n0 *= 0.125f; n1 *= 0.125f;
    }
    n0 = (n0 - *(const f32x4*)&mrS[t * 64 + oc8]) * *(const f32x4*)&mrS[192 + t * 64 + oc8];
    n1 = (n1 - *(const f32x4*)&mrS[t * 64 + oc8 + 4]) * *(const f32x4*)&mrS[192 + t * 64 + oc8 + 4];
    union { uint32_t u[4]; short8 v; } pc;
    pc.u[0] = pk2bf(n0[0], n0[1]);
    pc.u[1] = pk2bf(n0[2], n0[3]);
    pc.u[2] = pk2bf(n1[0], n1[1]);
    pc.u[3] = pk2bf(n1[2], n1[3]);
    const short8 br = pc.v;
    const short8 babs = br & (short)0x7FFF;
#pragma unroll
    for (int g = 0; g < 8; ++g) {
      const size_t wrow = (size_t)(g * 16 + lr) * 192 + ch0;
      const short8 a1a = *(const short8*)(W1A + wrow);
      const short8 a1b = *(const short8*)(W1B + wrow);
      const short8 asw = *(const short8*)(WS + wrow);
      accH[g] = __builtin_amdgcn_mfma_f32_16x16x32_bf16(a1a, br, accH[g], 0, 0, 0);
      accH[g] = __builtin_amdgcn_mfma_f32_16x16x32_bf16(a1b, babs, accH[g], 0, 0, 0);
      accO[g] = __builtin_amdgcn_mfma_f32_16x16x32_bf16(asw, br, accO[g], 0, 0, 0);
    }
  }

  // --- h = lrelu(accH + bias) -> wave-private LDS (no block barrier needed)
  unsigned short* Hs = &HsAll[wv][0];
#pragma unroll
  for (int g = 0; g < 8; ++g) {
    const int ocb = g * 16 + lg * 4;
    float bh0 = (ocb + 0 < 64) ? conv0_b[ocb + 0] : b3[ocb + 0 - 64];
    float bh1 = (ocb + 1 < 64) ? conv0_b[ocb + 1] : b3[ocb + 1 - 64];
    float bh2 = (ocb + 2 < 64) ? conv0_b[ocb + 2] : b3[ocb + 2 - 64];
    float bh3 = (ocb + 3 < 64) ? conv0_b[ocb + 3] : b3[ocb + 3 - 64];
    float h0 = accH[g][0] + bh0, h1 = accH[g][1] + bh1;
    float h2 = accH[g][2] + bh2, h3 = accH[g][3] + bh3;
    h0 = fmaxf(h0, 0.2f * h0); h1 = fmaxf(h1, 0.2f * h1);
    h2 = fmaxf(h2, 0.2f * h2); h3 = fmaxf(h3, 0.2f * h3);
    *(uint32_t*)(&Hs[lr * 138 + ocb])     = pk2bf(h0, h1);
    *(uint32_t*)(&Hs[lr * 138 + ocb + 2]) = pk2bf(h2, h3);
  }

  // --- GEMM2B: += W2 @ lrelu(h), K=128 (wave-local LDS read)
#pragma unroll
  for (int kc = 0; kc < 4; ++kc) {
    const int ko = kc * 32 + lg * 8;
    const short8 hb = *(const short8*)(&Hs[lr * 138 + ko]);
#pragma unroll
    for (int g = 0; g < 8; ++g) {
      const short8 a2 = *(const short8*)(W2 + (size_t)(g * 16 + lr) * 128 + ko);
      accO[g] = __builtin_amdgcn_mfma_f32_16x16x32_bf16(a2, hb, accO[g], 0, 0, 0);
    }
  }

  // --- epilogue: bias, GLU, noise, nxt = cur + lf*val
  const float lfv = fminf(fmaxf(leak_ptr[0], 0.001f), 1000.0f);
#pragma unroll
  for (int g = 0; g < 4; ++g) {
    const int ocb = g * 16 + lg * 4;
    const size_t adr = ((size_t)b * HW + (size_t)gr * W + gc) * 64 + ocb;
    const f32x4 cv = *(const f32x4*)(cur + adr);
    f32x4 ov;
#pragma unroll
    for (int r = 0; r < 4; ++r) {
      const int oca = ocb + r;
      const int ocg = oca + 64;
      const float boA = b3[192 + oca] + 0.1f * (conv1_b[oca] + b3[64 + oca]);
      const float boG = b3[192 + ocg] + 0.1f * (conv1_b[ocg] + b3[64 + ocg]);
      const float a = accO[g][r] + boA;
      const float gg = accO[g + 4][r] + boG;
      const float og = a * (1.0f / (1.0f + expf(-gg)));
      ov[r] = cv[r] + lfv * (og + noise_w_c[oca] * nzv);
    }
    *(f32x4*)(nxt + adr) = ov;
  }
}

// ---------------- fused bilinear-2x + gaussian (px-major) ----------------
__global__ __launch_bounds__(256) void k_upgauss(const float* __restrict__ src,
                                                 float* __restrict__ dst,
                                                 int H, int W, int loOW, int loOHW,
                                                 float ge, float gm) {
  const int idx = blockIdx.x * 256 + threadIdx.x;
  const int OHW = 1 << loOHW;
  if (idx >= B_ * OHW * 16) return;
  const int chq = idx & 15;
  const int opx = (idx >> 4) & (OHW - 1);
  const int b = idx >> (4 + loOHW);
  const int oh = opx >> loOW, ow = opx & ((1 << loOW) - 1);
  const float g[3] = {ge, gm, ge};

  float wy[3] = {0.f, 0.f, 0.f}, wx[3] = {0.f, 0.f, 0.f};
  const int myi = oh >> 1, mxi = ow >> 1;
#pragma unroll
  for (int d = -1; d <= 1; ++d) {
    {
      const int oo = oh + d;
      if (oo >= 0 && oo < 2 * H) {
        const int i0 = (oo - 1) >> 1;
        const float f = ((oo - 1) & 1) ? 0.75f : 0.25f;
        const int i0c = max(i0, 0), i1c = min(i0 + 1, H - 1);
        wy[i0c - (myi - 1)] += g[d + 1] * (1.f - f);
        wy[i1c - (myi - 1)] += g[d + 1] * f;
      }
    }
    {
      const int oo = ow + d;
      if (oo >= 0 && oo < 2 * W) {
        const int i0 = (oo - 1) >> 1;
        const float f = ((oo - 1) & 1) ? 0.75f : 0.25f;
        const int i0c = max(i0, 0), i1c = min(i0 + 1, W - 1);
        wx[i0c - (mxi - 1)] += g[d + 1] * (1.f - f);
        wx[i1c - (mxi - 1)] += g[d + 1] * f;
      }
    }
  }
  const float* pl = src + ((size_t)b * H * W) * 64 + chq * 4;
  f32x4 acc = (f32x4)0.f;
#pragma unroll
  for (int i = 0; i < 3; ++i) {
    const int ry = min(max(myi - 1 + i, 0), H - 1);
    f32x4 rowv = (f32x4)0.f;
#pragma unroll
    for (int j = 0; j < 3; ++j) {
      const int rx = min(max(mxi - 1 + j, 0), W - 1);
      rowv += wx[j] * *(const f32x4*)(pl + (size_t)(ry * W + rx) * 64);
    }
    acc += wy[i] * rowv;
  }
  *(f32x4*)(dst + ((size_t)b * OHW + opx) * 64 + chq * 4) = acc;
}

// ---------------- final 1x1 conv + clip ----------------
__global__ __launch_bounds__(256) void k_final(const float* __restrict__ outbuf,
                                               const float* __restrict__ out_w,
                                               const float* __restrict__ out_b,
                                               float* __restrict__ dout) {
  const int idx = blockIdx.x * 256 + threadIdx.x;
  const int b = idx >> 14, px = idx & 16383;
  const float* src = outbuf + ((size_t)b * 16384 + px) * 64;
  float a0 = out_b[0], a1 = out_b[1], a2 = out_b[2];
  for (int i = 0; i < 64; i += 4) {
    const f32x4 v = *(const f32x4*)(src + i);
    const f32x4 w0 = *(const f32x4*)(out_w + i);
    const f32x4 w1 = *(const f32x4*)(out_w + 64 + i);
    const f32x4 w2 = *(const f32x4*)(out_w + 128 + i);
#pragma unroll
    for (int e = 0; e < 4; ++e) {
      a0 = fmaf(w0[e], v[e], a0);
      a1 = fmaf(w1[e], v[e], a1);
      a2 = fmaf(w2[e], v[e], a2);
    }
  }
  const size_t base = (size_t)b * 49152 + px;
  dout[base] = fminf(fmaxf(a0, -1.f), 1.f);
  dout[base + 16384] = fminf(fmaxf(a1, -1.f), 1.f);
  dout[base + 32768] = fminf(fmaxf(a2, -1.f), 1.f);
  dout[393216 + base] = a0;
  dout[393216 + base + 16384] = a1;
  dout[393216 + base + 32768] = a2;
}

// ---------------- host launch ----------------
extern "C" void kernel_launch(void* const* d_in, const int* in_sizes, int n_in,
                              void* d_out, int out_size, void* d_ws, size_t ws_size,
                              hipStream_t stream) {
  const float* lat       = (const float*)d_in[0];
  const float* seed      = (const float*)d_in[1];
  const float* leak      = (const float*)d_in[2];
  const float* lat_exp_w = (const float*)d_in[3];
  const float* lat_exp_b = (const float*)d_in[4];
  const float* noise_w   = (const float*)d_in[5];
  const float* dyna_w    = (const float*)d_in[6];
  const float* dyna_b    = (const float*)d_in[7];
  const float* conv0_w   = (const float*)d_in[8];
  const float* conv0_b   = (const float*)d_in[9];
  const float* conv1_w   = (const float*)d_in[10];
  const float* conv1_b   = (const float*)d_in[11];
  const float* convs_w   = (const float*)d_in[12];
  const float* out_w     = (const float*)d_in[13];
  const float* out_b     = (const float*)d_in[14];

  float* wsf = (float*)d_ws;
  float* part = wsf + OFF_PART;
  float* b3   = wsf + OFF_B3;
  unsigned short* latc_bf = (unsigned short*)(wsf + OFF_LATCBF);
  float* out0 = wsf + OFF_OUT0;
  float* out1 = wsf + OFF_OUT1;
  unsigned short* wpk = (unsigned short*)(wsf + OFF_WPK);

  uint32_t lk0[NLAY_], lk1[NLAY_];
  for (int c = 0; c < NLAY_; ++c)
    host_tf_cipher(0u, 7u, 0u, (uint32_t)c, lk0[c], lk1[c]);

  const double ga = exp(-0.5);
  const float ge = (float)(ga / (1.0 + 2.0 * ga));
  const float gm = (float)(1.0 / (1.0 + 2.0 * ga));

  k_seed<<<(B_ * 256 * 64) / 256, 256, 0, stream>>>(seed, out0);
  k_latc<<<NLAY_, 256, 0, stream>>>(lat, lat_exp_w, lat_exp_b, latc_bf);
  k_wstatic<<<NLAY_ * B_, 256, 0, stream>>>(conv0_w, conv1_w, wpk);
  k_ks<<<P_ / 64, 256, 0, stream>>>(latc_bf, dyna_w, dyna_b, convs_w, wpk, b3);

  float* cur = out0;
  float* nxt = out1;
  int H = 16, W = 16, logW = 4;
  for (int c = 0; c < NLAY_; ++c) {
    const int HW = H * W;
    const int NS = (HW >= 16384) ? 32 : ((HW >= 4096) ? 16 : ((HW >= 1024) ? 8 : 4));
    k_stats1<<<dim3(NS, B_), 256, 0, stream>>>(cur, part, H, W, logW, HW, NS);
    k_main<<<dim3(HW / 64, B_), 256, 0, stream>>>(
        cur, nxt, part,
        wpk + (size_t)c * B_ * WPK_STRIDE, b3 + (size_t)c * B_ * 320,
        conv0_b, conv1_b, noise_w + c * F0_, leak,
        HW, W, logW - 4, NS, lk0[c], lk1[c]);
    { float* t = cur; cur = nxt; nxt = t; }
    if ((c & 3) == 3 && c < NLAY_ - 1) {
      const int n1 = B_ * 4 * HW * 16;
      const int loOW = logW + 1, loOHW = 2 * logW + 2;
      k_upgauss<<<(n1 + 255) / 256, 256, 0, stream>>>(cur, nxt, H, W, loOW, loOHW, ge, gm);
      { float* t = cur; cur = nxt; nxt = t; }
      H *= 2; W *= 2; logW += 1;
    }
  }
  k_final<<<(B_ * 16384) / 256, 256, 0, stream>>>(cur, out_w, out_b, (float*)d_out);
  (void)in_sizes; (void)n_in; (void)out_size; (void)ws_size;
}

// Round 10
// 872.837 us; speedup vs baseline: 2.0738x; 2.0738x over previous
//
#include <hip/hip_runtime.h>
#include <cstdint>
#include <cstddef>
#include <cmath>

#define DI __device__ __forceinline__

constexpr int B_ = 8;
constexpr int F0_ = 64;
constexpr int LAT_ = 512;
constexpr int P_ = 45376;
constexpr int NLAY_ = 16;

typedef __attribute__((ext_vector_type(8))) short short8;
typedef __attribute__((ext_vector_type(4))) float f32x4;

// wpk per-(c,b) slot (bf16): W1A(0.6*W1)[128][192] | W1B(0.4*W1)[128][192] |
//                            WS[128][192] | W2(0.1*)[128][128]
constexpr int WPK_STRIDE = 90112;
constexpr int WPK_W1B = 24576;
constexpr int WPK_WS  = 49152;
constexpr int WPK_W2  = 73728;

// ---- workspace layout (float offsets). out buffers PX-MAJOR: out[b][px][64ch]
constexpr size_t OFF_PART   = 0;          // 8*32*384 = 98304
constexpr size_t OFF_B3     = 98304;      // 40960
constexpr size_t OFF_LATCBF = 139264;     // 32768
constexpr size_t OFF_OUT0   = 172032;     // 8388608
constexpr size_t OFF_OUT1   = 8560640;    // 8388608
constexpr size_t OFF_WPK    = 16949248;   // 128*90112 u16 = 5767168 f -> end ~90.9 MB

DI uint16_t f2bf(float f) {
  uint32_t u = __float_as_uint(f);
  uint32_t r = (u + 0x7FFFu + ((u >> 16) & 1u)) >> 16;
  return (uint16_t)r;
}
DI uint32_t pk2bf(float a, float b) {
  return (uint32_t)f2bf(a) | ((uint32_t)f2bf(b) << 16);
}

// ---------------- threefry2x32 ----------------
DI void tf_cipher(uint32_t k0, uint32_t k1, uint32_t x0, uint32_t x1,
                  uint32_t& o0, uint32_t& o1) {
  const uint32_t ks2 = k0 ^ k1 ^ 0x1BD11BDAu;
  uint32_t a = x0 + k0, b = x1 + k1;
#define TFR(r) { a += b; b = (b << (r)) | (b >> (32 - (r))); b ^= a; }
  TFR(13) TFR(15) TFR(26) TFR(6)  a += k1;  b += ks2 + 1u;
  TFR(17) TFR(29) TFR(16) TFR(24) a += ks2; b += k0 + 2u;
  TFR(13) TFR(15) TFR(26) TFR(6)  a += k0;  b += k1 + 3u;
  TFR(17) TFR(29) TFR(16) TFR(24) a += k1;  b += ks2 + 4u;
  TFR(13) TFR(15) TFR(26) TFR(6)  a += ks2; b += k0 + 5u;
#undef TFR
  o0 = a; o1 = b;
}

static void host_tf_cipher(uint32_t k0, uint32_t k1, uint32_t x0, uint32_t x1,
                           uint32_t& o0, uint32_t& o1) {
  const uint32_t ks2 = k0 ^ k1 ^ 0x1BD11BDAu;
  uint32_t a = x0 + k0, b = x1 + k1;
#define TFR(r) { a += b; b = (b << (r)) | (b >> (32 - (r))); b ^= a; }
  TFR(13) TFR(15) TFR(26) TFR(6)  a += k1;  b += ks2 + 1u;
  TFR(17) TFR(29) TFR(16) TFR(24) a += ks2; b += k0 + 2u;
  TFR(13) TFR(15) TFR(26) TFR(6)  a += k0;  b += k1 + 3u;
  TFR(17) TFR(29) TFR(16) TFR(24) a += k1;  b += ks2 + 4u;
  TFR(13) TFR(15) TFR(26) TFR(6)  a += ks2; b += k0 + 5u;
#undef TFR
  o0 = a; o1 = b;
}

DI float erfinv_f(float x) {
  float w = -log1pf(-x * x);
  float p;
  if (w < 5.0f) {
    w = w - 2.5f;
    p = 2.81022636e-08f;
    p = fmaf(p, w, 3.43273939e-07f);
    p = fmaf(p, w, -3.5233877e-06f);
    p = fmaf(p, w, -4.39150654e-06f);
    p = fmaf(p, w, 0.00021858087f);
    p = fmaf(p, w, -0.00125372503f);
    p = fmaf(p, w, -0.00417768164f);
    p = fmaf(p, w, 0.246640727f);
    p = fmaf(p, w, 1.50140941f);
  } else {
    w = sqrtf(w) - 3.0f;
    p = -0.000200214257f;
    p = fmaf(p, w, 0.000100950558f);
    p = fmaf(p, w, 0.00134934322f);
    p = fmaf(p, w, -0.00367342844f);
    p = fmaf(p, w, 0.00573950773f);
    p = fmaf(p, w, -0.0076224613f);
    p = fmaf(p, w, 0.00943887047f);
    p = fmaf(p, w, 1.00167406f);
    p = fmaf(p, w, 2.83297682f);
  }
  return p * x;
}

DI float noise_val(uint32_t k0, uint32_t k1, uint32_t idx) {
  uint32_t o0, o1;
  tf_cipher(k0, k1, 0u, idx, o0, o1);
  uint32_t bits = o0 ^ o1;
  float f = __uint_as_float((bits >> 9) | 0x3f800000u) - 1.0f;
  const float lo = -0.99999994f;
  float u = fmaxf(lo, fmaf(f, 2.0f, lo));
  return 1.41421354f * erfinv_f(u);
}

// ---------------- seed broadcast ----------------
__global__ __launch_bounds__(256) void k_seed(const float* __restrict__ seed,
                                              float* __restrict__ outb) {
  const int idx = blockIdx.x * 256 + threadIdx.x;
  const int px = (idx >> 6) & 255, ch = idx & 63;
  outb[idx] = seed[ch * 256 + px];
}

// ---------------- latc (bf16) ----------------
__global__ __launch_bounds__(256) void k_latc(const float* __restrict__ lat,
                                              const float* __restrict__ wexp,
                                              const float* __restrict__ bexp,
                                              unsigned short* __restrict__ latc_bf) {
  const int c = blockIdx.x;
  const int tid = threadIdx.x;
  __shared__ float latS[B_][LAT_];
  for (int i = tid; i < B_ * LAT_; i += 256) latS[i >> 9][i & 511] = lat[i];
  __syncthreads();
  for (int o = tid; o < LAT_; o += 256) {
    float acc[B_] = {0, 0, 0, 0, 0, 0, 0, 0};
    const float* wr = wexp + ((size_t)c * LAT_ + o) * LAT_;
    for (int k = 0; k < LAT_; k += 4) {
      float4 w4 = *(const float4*)(wr + k);
#pragma unroll
      for (int b = 0; b < B_; ++b) {
        acc[b] = fmaf(w4.x, latS[b][k + 0], acc[b]);
        acc[b] = fmaf(w4.y, latS[b][k + 1], acc[b]);
        acc[b] = fmaf(w4.z, latS[b][k + 2], acc[b]);
        acc[b] = fmaf(w4.w, latS[b][k + 3], acc[b]);
      }
    }
    const float bb = bexp[c * LAT_ + o];
#pragma unroll
    for (int b = 0; b < B_; ++b)
      latc_bf[((size_t)c * B_ + b) * LAT_ + o] = f2bf(acc[b] + bb);
  }
}

// ---------------- static weight fill ----------------
__global__ __launch_bounds__(256) void k_wstatic(const float* __restrict__ conv0_w,
                                                 const float* __restrict__ conv1_w,
                                                 unsigned short* __restrict__ wpk) {
  const int cb = blockIdx.x;
  unsigned short* wq = wpk + (size_t)cb * WPK_STRIDE;
  for (int i = threadIdx.x; i < 64 * 192; i += 256) {
    const float v = conv0_w[i];
    wq[i] = f2bf(0.6f * v);
    wq[WPK_W1B + i] = f2bf(0.4f * v);
  }
  for (int i = threadIdx.x; i < 128 * 64; i += 256) {
    int oc = i >> 6, k = i & 63;
    wq[WPK_W2 + oc * 128 + k] = f2bf(0.1f * conv1_w[i]);
  }
}

// ---------------- ks via bf16 MFMA ----------------
__global__ __launch_bounds__(256) void k_ks(
    const unsigned short* __restrict__ latc_bf,
    const float* __restrict__ dyna_w,
    const float* __restrict__ dyna_b,
    const float* __restrict__ convs_w,
    unsigned short* __restrict__ wpk,
    float* __restrict__ bias3) {
  const int n0 = blockIdx.x * 64;
  const int tid = threadIdx.x;
  const int wv = tid >> 6, lane = tid & 63, lg = lane >> 4, lr = lane & 15;
  __shared__ __align__(16) unsigned char AsB[128 * 64];
  __shared__ __align__(16) unsigned char BsB[64 * 64];

  f32x4 acc[2][4];
#pragma unroll
  for (int i = 0; i < 2; ++i)
#pragma unroll
    for (int j = 0; j < 4; ++j) acc[i][j] = (f32x4)0.f;

  const int am = tid >> 1, ah = tid & 1;
  const int bn = tid >> 2, bq = tid & 3;

  for (int kc = 0; kc < LAT_; kc += 32) {
    __syncthreads();
    {
      const uint4* src = (const uint4*)(latc_bf + (size_t)am * LAT_ + kc + ah * 16);
      const uint4 u0 = src[0];
      const uint4 u1 = src[1];
      const int swz = (am & 7) << 4;
      *(uint4*)(AsB + ((am * 64 + ah * 32) ^ swz)) = u0;
      *(uint4*)(AsB + ((am * 64 + ah * 32 + 16) ^ swz)) = u1;
    }
    {
      const float* src = dyna_w + (size_t)(n0 + bn) * LAT_ + kc + bq * 8;
      const float4 f0 = *(const float4*)(src);
      const float4 f1 = *(const float4*)(src + 4);
      uint4 u;
      u.x = pk2bf(f0.x, f0.y);
      u.y = pk2bf(f0.z, f0.w);
      u.z = pk2bf(f1.x, f1.y);
      u.w = pk2bf(f1.z, f1.w);
      *(uint4*)(BsB + ((bn * 64 + bq * 16) ^ ((bn & 7) << 4))) = u;
    }
    __syncthreads();
    short8 af[2], bfx[4];
#pragma unroll
    for (int mt = 0; mt < 2; ++mt) {
      const int rm = wv * 32 + mt * 16 + lr;
      af[mt] = *(const short8*)(AsB + ((rm * 64 + lg * 16) ^ ((rm & 7) << 4)));
    }
#pragma unroll
    for (int nt = 0; nt < 4; ++nt) {
      const int rn = nt * 16 + lr;
      bfx[nt] = *(const short8*)(BsB + ((rn * 64 + lg * 16) ^ ((rn & 7) << 4)));
    }
#pragma unroll
    for (int mt = 0; mt < 2; ++mt)
#pragma unroll
      for (int nt = 0; nt < 4; ++nt)
        acc[mt][nt] = __builtin_amdgcn_mfma_f32_16x16x32_bf16(af[mt], bfx[nt], acc[mt][nt], 0, 0, 0);
  }

#pragma unroll
  for (int nt = 0; nt < 4; ++nt) {
    const int n = n0 + nt * 16 + lr;
    int typ, e_off;
    float addv = 0.f;
    if (n < 12288) { int oc = n / 192; int k = n - oc * 192; typ = 0; e_off = (64 + oc) * 192 + k; }
    else if (n < 12352) { typ = 1; e_off = n - 12288; }
    else if (n < 20544) { int m2 = n - 12352; typ = 2; e_off = WPK_W2 + (m2 >> 6) * 128 + 64 + (m2 & 63); }
    else if (n < 20672) { typ = 3; e_off = 64 + (n - 20544); }
    else if (n < 45248) {
      int m3 = n - 20672; int oc = m3 / 192; int k = m3 - oc * 192;
      typ = 4; e_off = WPK_WS + oc * 192 + k; addv = convs_w[oc * 192 + k];
    } else { typ = 5; e_off = 192 + (n - 45248); }
    const float db = dyna_b[n];
#pragma unroll
    for (int mt = 0; mt < 2; ++mt) {
#pragma unroll
      for (int reg = 0; reg < 4; ++reg) {
        const int cb = wv * 32 + mt * 16 + lg * 4 + reg;
        float v = acc[mt][nt][reg] + db;
        if (typ == 4) v += addv;
        if (typ == 2) v *= 0.1f;
        if (typ == 0) {
          wpk[(size_t)cb * WPK_STRIDE + e_off] = f2bf(0.6f * v);
          wpk[(size_t)cb * WPK_STRIDE + WPK_W1B + e_off] = f2bf(0.4f * v);
        } else if (typ == 2 || typ == 4) {
          wpk[(size_t)cb * WPK_STRIDE + e_off] = f2bf(v);
        } else {
          bias3[(size_t)cb * 320 + e_off] = v;
        }
      }
    }
  }
}

DI f32x4 ldc(const float* p, bool c) { return c ? *(const f32x4*)p : (f32x4)0.f; }

// sliding-window column loader: sv = r0+2r1+r2, dv = r2-r0, cm = r1 (zero-pad)
DI void loadcol(const float* base, int gc2, int W, bool vu, bool vd, int rW,
                f32x4& sv, f32x4& dv, f32x4& cm) {
  if (gc2 < 0 || gc2 >= W) { sv = (f32x4)0.f; dv = (f32x4)0.f; cm = (f32x4)0.f; return; }
  const float* cp = base + (size_t)gc2 * 64;
  const f32x4 a = vu ? *(const f32x4*)(cp - rW) : (f32x4)0.f;
  const f32x4 m = *(const f32x4*)(cp);
  const f32x4 d = vd ? *(const f32x4*)(cp + rW) : (f32x4)0.f;
  sv = a + 2.f * m + d;
  dv = d - a;
  cm = m;
}

// ---------------- stats pass (px-major, NS strip partials, sliding window) ----------------
__global__ __launch_bounds__(256) void k_stats1(const float* __restrict__ cur,
                                                float* __restrict__ part,
                                                int H, int W, int logW, int HW,
                                                int NS) {
  const int b = blockIdx.y;
  const int strip = blockIdx.x;
  const int tid = threadIdx.x;
  const int chq = tid & 15, run0 = (tid >> 4) & 3, wv = tid >> 6;
  const int pxs = HW / NS;
  const int p0 = strip * pxs;
  const float* __restrict__ ob = cur + (size_t)b * HW * 64 + chq * 4;
  const int rW = W * 64;

  f32x4 s[6];
#pragma unroll
  for (int i = 0; i < 6; ++i) s[i] = (f32x4)0.f;

  // each thread: runs of 4 contiguous px (never crossing a row, since W%4==0)
  for (int pr = (p0 >> 2) + wv * 4 + run0; pr < (p0 + pxs) >> 2; pr += 16) {
    const int px0 = pr * 4;
    const int h = px0 >> logW, w0 = px0 & (W - 1);
    const bool vu = h > 0, vd = h < H - 1;
    const float* rowb = ob + ((size_t)h * W) * 64;
    f32x4 svp, dvp, cmp_, sv0, dv0, cm0;
    loadcol(rowb, w0 - 1, W, vu, vd, rW, svp, dvp, cmp_);
    loadcol(rowb, w0, W, vu, vd, rW, sv0, dv0, cm0);
#pragma unroll
    for (int j = 0; j < 4; ++j) {
      f32x4 svn, dvn, cmn;
      loadcol(rowb, w0 + j + 1, W, vu, vd, rW, svn, dvn, cmn);
      const f32x4 vx = (svn - svp) * 0.125f;
      const f32x4 vy = (dvp + 2.f * dv0 + dvn) * 0.125f;
      s[0] += vx; s[1] += vx * vx;
      s[2] += vy; s[3] += vy * vy;
      s[4] += cm0; s[5] += cm0 * cm0;
      svp = sv0; dvp = dv0; sv0 = svn; dv0 = dvn; cm0 = cmn;
    }
  }
#pragma unroll
  for (int i = 0; i < 6; ++i)
#pragma unroll
    for (int c = 0; c < 4; ++c) {
      s[i][c] += __shfl_xor(s[i][c], 16, 64);
      s[i][c] += __shfl_xor(s[i][c], 32, 64);
    }
  __shared__ f32x4 redS[64][6];
  if ((tid & 63) < 16) {
#pragma unroll
    for (int i = 0; i < 6; ++i) redS[wv * 16 + chq][i] = s[i];
  }
  __syncthreads();
  if (tid < 16) {
    f32x4 a[6];
#pragma unroll
    for (int i = 0; i < 6; ++i)
      a[i] = redS[tid][i] + redS[16 + tid][i] + redS[32 + tid][i] + redS[48 + tid][i];
    float* pp = part + (size_t)(b * NS + strip) * 384;
#pragma unroll
    for (int i = 0; i < 6; ++i) {
      const int sec = i >> 1, wbit = i & 1;
#pragma unroll
      for (int c = 0; c < 4; ++c)
        pp[sec * 128 + wbit * 64 + tid * 4 + c] = a[i][c];
    }
  }
}

// ---------------- fused main layer (px-major): sliding-window p + MFMA + GLU ----------------
__global__ __launch_bounds__(256, 4) void k_main(
    const float* __restrict__ cur, float* __restrict__ nxt,
    const float* __restrict__ part,
    const unsigned short* __restrict__ wpk_layer,
    const float* __restrict__ bias3_layer,
    const float* __restrict__ conv0_b,
    const float* __restrict__ conv1_b,
    const float* __restrict__ noise_w_c,
    const float* __restrict__ leak_ptr,
    int HW, int W, int lwpr, int NS, unsigned key0, unsigned key1) {
  const int b = blockIdx.y;
  const int bx = blockIdx.x;
  const int tr = bx >> lwpr, tc = bx & ((1 << lwpr) - 1);
  const int r0 = tr * 4, c0 = tc * 16;
  const int logW = lwpr + 4;
  const int H = HW >> logW;

  const int tid = threadIdx.x;
  const int wv = tid >> 6, lane = tid & 63;
  const int lg = lane >> 4, lr = lane & 15;

  __shared__ __align__(16) unsigned char PrawB[24576];
  __shared__ float mrS[384];
  __shared__ float noiseS[64];
  unsigned short* Hs = (unsigned short*)PrawB;  // aliases Praw after GEMM1/2A

  const unsigned short* wq = wpk_layer + (size_t)b * WPK_STRIDE;
  const unsigned short* W1A = wq;
  const unsigned short* W1B = wq + WPK_W1B;
  const unsigned short* WS  = wq + WPK_WS;
  const unsigned short* W2  = wq + WPK_W2;
  const float* b3 = bias3_layer + (size_t)b * 320;

  // --- prologue: merge strip partials -> m/r; per-px noise
  if (tid < 192) {
    const int sec = tid >> 6, ch = tid & 63;
    const float* pb = part + (size_t)b * NS * 384;
    float s1 = 0.f, s2 = 0.f;
    for (int st = 0; st < NS; ++st) {
      s1 += pb[st * 384 + sec * 128 + ch];
      s2 += pb[st * 384 + sec * 128 + 64 + ch];
    }
    const float inv = 1.0f / (float)HW;
    const float m = s1 * inv;
    mrS[sec * 64 + ch] = m;
    mrS[192 + sec * 64 + ch] = rsqrtf(fmaxf(s2 * inv - m * m, 0.f) + 1e-5f);
  }
  if (tid < 64)
    noiseS[tid] = noise_val(key0, key1,
        (unsigned)(b * HW + (r0 + (tid >> 4)) * W + c0 + (tid & 15)));
  __syncthreads();

  // --- phase A: sliding-window sobel+inorm -> bf16 p in LDS
  {
    const int pxi = lane >> 4;   // run of 4 cols: cl = pxi*4 + j
    const int chq = lane & 15;   // ch quad
    const int ch = chq * 4;
    const int gr = r0 + wv;      // wave owns one tile row
    const bool vu = gr > 0, vd = gr < H - 1;
    const int rW = W * 64;
    const float* rowb = cur + ((size_t)b * HW + (size_t)gr * W) * 64 + ch;
    const int gc0 = c0 + pxi * 4;

    const f32x4 mx = *(const f32x4*)&mrS[ch];
    const f32x4 rx = *(const f32x4*)&mrS[192 + ch];
    const f32x4 my = *(const f32x4*)&mrS[64 + ch];
    const f32x4 ry = *(const f32x4*)&mrS[192 + 64 + ch];
    const f32x4 mi = *(const f32x4*)&mrS[128 + ch];
    const f32x4 ri = *(const f32x4*)&mrS[192 + 128 + ch];

    f32x4 svp, dvp, cmp_, sv0, dv0, cm0;
    loadcol(rowb, gc0 - 1, W, vu, vd, rW, svp, dvp, cmp_);
    loadcol(rowb, gc0, W, vu, vd, rW, sv0, dv0, cm0);
#pragma unroll
    for (int j = 0; j < 4; ++j) {
      f32x4 svn, dvn, cmn;
      loadcol(rowb, gc0 + j + 1, W, vu, vd, rW, svn, dvn, cmn);
      const f32x4 vx = (svn - svp) * 0.125f;
      const f32x4 vy = (dvp + 2.f * dv0 + dvn) * 0.125f;
      const f32x4 nx = (vx - mx) * rx;
      const f32x4 ny = (vy - my) * ry;
      const f32x4 ni = (cm0 - mi) * ri;
      const int pxl = wv * 16 + pxi * 4 + j;
      const int swz = (pxl & 7) << 4;
      const int bb = pxl * 384 + ch * 2;
      uint2 u;
      u.x = pk2bf(nx[0], nx[1]); u.y = pk2bf(nx[2], nx[3]);
      *(uint2*)(PrawB + ((bb) ^ swz)) = u;
      u.x = pk2bf(ny[0], ny[1]); u.y = pk2bf(ny[2], ny[3]);
      *(uint2*)(PrawB + ((bb + 128) ^ swz)) = u;
      u.x = pk2bf(ni[0], ni[1]); u.y = pk2bf(ni[2], ni[3]);
      *(uint2*)(PrawB + ((bb + 256) ^ swz)) = u;
      svp = sv0; dvp = dv0; sv0 = svn; dv0 = dvn; cm0 = cmn;
    }
  }
  __syncthreads();

  // --- phase B: GEMM1 via lrelu(p)=0.6p+0.4|p| split, + GEMM2A (WS @ p), K=192
  //     two weight groups per kc to cap live VGPRs
  const int oc0 = 16 * wv;
  const int oc1 = 64 + 16 * wv;
  f32x4 accH[2][4], accO[2][4];
#pragma unroll
  for (int t = 0; t < 2; ++t)
#pragma unroll
    for (int p = 0; p < 4; ++p) { accH[t][p] = (f32x4)0.f; accO[t][p] = (f32x4)0.f; }

#pragma unroll
  for (int kc = 0; kc < 6; ++kc) {
    const int ko = kc * 32 + lg * 8;
    {
      const short8 a1a0 = *(const short8*)(W1A + (size_t)(oc0 + lr) * 192 + ko);
      const short8 a1a1 = *(const short8*)(W1A + (size_t)(oc1 + lr) * 192 + ko);
      const short8 a1b0 = *(const short8*)(W1B + (size_t)(oc0 + lr) * 192 + ko);
      const short8 a1b1 = *(const short8*)(W1B + (size_t)(oc1 + lr) * 192 + ko);
#pragma unroll
      for (int pxt = 0; pxt < 4; ++pxt) {
        const int px = pxt * 16 + lr;
        const int byt = (px * 384 + ko * 2) ^ ((px & 7) << 4);
        const short8 br = *(const short8*)(PrawB + byt);
        const short8 babs = br & (short)0x7FFF;
        accH[0][pxt] = __builtin_amdgcn_mfma_f32_16x16x32_bf16(a1a0, br, accH[0][pxt], 0, 0, 0);
        accH[1][pxt] = __builtin_amdgcn_mfma_f32_16x16x32_bf16(a1a1, br, accH[1][pxt], 0, 0, 0);
        accH[0][pxt] = __builtin_amdgcn_mfma_f32_16x16x32_bf16(a1b0, babs, accH[0][pxt], 0, 0, 0);
        accH[1][pxt] = __builtin_amdgcn_mfma_f32_16x16x32_bf16(a1b1, babs, accH[1][pxt], 0, 0, 0);
      }
    }
    {
      const short8 as0 = *(const short8*)(WS + (size_t)(oc0 + lr) * 192 + ko);
      const short8 as1 = *(const short8*)(WS + (size_t)(oc1 + lr) * 192 + ko);
#pragma unroll
      for (int pxt = 0; pxt < 4; ++pxt) {
        const int px = pxt * 16 + lr;
        const int byt = (px * 384 + ko * 2) ^ ((px & 7) << 4);
        const short8 br = *(const short8*)(PrawB + byt);
        accO[0][pxt] = __builtin_amdgcn_mfma_f32_16x16x32_bf16(as0, br, accO[0][pxt], 0, 0, 0);
        accO[1][pxt] = __builtin_amdgcn_mfma_f32_16x16x32_bf16(as1, br, accO[1][pxt], 0, 0, 0);
      }
    }
  }
  __syncthreads();  // all Praw reads done before Hs overwrites

  // h = lrelu(acc + bias) -> Hs
#pragma unroll
  for (int ti = 0; ti < 2; ++ti) {
    const int ocb = ti ? oc1 : oc0;
    float bh[4];
#pragma unroll
    for (int r = 0; r < 4; ++r) {
      const int oc = ocb + lg * 4 + r;
      bh[r] = (oc < 64) ? conv0_b[oc] : b3[oc - 64];
    }
#pragma unroll
    for (int pxt = 0; pxt < 4; ++pxt) {
      const int px = pxt * 16 + lr;
#pragma unroll
      for (int rp = 0; rp < 2; ++rp) {
        float h0 = accH[ti][pxt][rp * 2 + 0] + bh[rp * 2 + 0];
        float h1 = accH[ti][pxt][rp * 2 + 1] + bh[rp * 2 + 1];
        h0 = fmaxf(h0, 0.2f * h0);
        h1 = fmaxf(h1, 0.2f * h1);
        *(uint32_t*)(&Hs[(size_t)px * 136 + ocb + lg * 4 + rp * 2]) = pk2bf(h0, h1);
      }
    }
  }
  __syncthreads();

  // --- GEMM2B: += W2 @ lrelu(h), K=128
#pragma unroll
  for (int kc = 0; kc < 4; ++kc) {
    const int ko = kc * 32 + lg * 8;
    const short8 a20 = *(const short8*)(W2 + (size_t)(oc0 + lr) * 128 + ko);
    const short8 a21 = *(const short8*)(W2 + (size_t)(oc1 + lr) * 128 + ko);
#pragma unroll
    for (int pxt = 0; pxt < 4; ++pxt) {
      const short8 hb = *(const short8*)(&Hs[(size_t)(pxt * 16 + lr) * 136 + ko]);
      accO[0][pxt] = __builtin_amdgcn_mfma_f32_16x16x32_bf16(a20, hb, accO[0][pxt], 0, 0, 0);
      accO[1][pxt] = __builtin_amdgcn_mfma_f32_16x16x32_bf16(a21, hb, accO[1][pxt], 0, 0, 0);
    }
  }

  // --- epilogue: bias, GLU, noise, nxt = cur + lf*val
  const float lfv = fminf(fmaxf(leak_ptr[0], 0.001f), 1000.0f);
  float boA[4], boG[4], nw[4];
#pragma unroll
  for (int r = 0; r < 4; ++r) {
    const int oca = oc0 + lg * 4 + r;
    const int ocg = oc1 + lg * 4 + r;
    boA[r] = b3[192 + oca] + 0.1f * (conv1_b[oca] + b3[64 + oca]);
    boG[r] = b3[192 + ocg] + 0.1f * (conv1_b[ocg] + b3[64 + ocg]);
    nw[r] = noise_w_c[oca];
  }
#pragma unroll
  for (int pxt = 0; pxt < 4; ++pxt) {
    const float nz = noiseS[pxt * 16 + lr];
    const size_t adr = ((size_t)b * HW + (size_t)(r0 + pxt) * W + c0 + lr) * 64 + oc0 + lg * 4;
    const f32x4 cv = *(const f32x4*)(cur + adr);
    f32x4 ov;
#pragma unroll
    for (int r = 0; r < 4; ++r) {
      const float a = accO[0][pxt][r] + boA[r];
      const float g = accO[1][pxt][r] + boG[r];
      const float og = a * (1.0f / (1.0f + expf(-g)));
      ov[r] = cv[r] + lfv * (og + nw[r] * nz);
    }
    *(f32x4*)(nxt + adr) = ov;
  }
}

// ---------------- fused bilinear-2x + gaussian (px-major) ----------------
__global__ __launch_bounds__(256) void k_upgauss(const float* __restrict__ src,
                                                 float* __restrict__ dst,
                                                 int H, int W, int loOW, int loOHW,
                                                 float ge, float gm) {
  const int idx = blockIdx.x * 256 + threadIdx.x;
  const int OHW = 1 << loOHW;
  if (idx >= B_ * OHW * 16) return;
  const int chq = idx & 15;
  const int opx = (idx >> 4) & (OHW - 1);
  const int b = idx >> (4 + loOHW);
  const int oh = opx >> loOW, ow = opx & ((1 << loOW) - 1);
  const float g[3] = {ge, gm, ge};

  float wy[3] = {0.f, 0.f, 0.f}, wx[3] = {0.f, 0.f, 0.f};
  const int myi = oh >> 1, mxi = ow >> 1;
#pragma unroll
  for (int d = -1; d <= 1; ++d) {
    {
      const int oo = oh + d;
      if (oo >= 0 && oo < 2 * H) {
        const int i0 = (oo - 1) >> 1;
        const float f = ((oo - 1) & 1) ? 0.75f : 0.25f;
        const int i0c = max(i0, 0), i1c = min(i0 + 1, H - 1);
        wy[i0c - (myi - 1)] += g[d + 1] * (1.f - f);
        wy[i1c - (myi - 1)] += g[d + 1] * f;
      }
    }
    {
      const int oo = ow + d;
      if (oo >= 0 && oo < 2 * W) {
        const int i0 = (oo - 1) >> 1;
        const float f = ((oo - 1) & 1) ? 0.75f : 0.25f;
        const int i0c = max(i0, 0), i1c = min(i0 + 1, W - 1);
        wx[i0c - (mxi - 1)] += g[d + 1] * (1.f - f);
        wx[i1c - (mxi - 1)] += g[d + 1] * f;
      }
    }
  }
  const float* pl = src + ((size_t)b * H * W) * 64 + chq * 4;
  f32x4 acc = (f32x4)0.f;
#pragma unroll
  for (int i = 0; i < 3; ++i) {
    const int ry = min(max(myi - 1 + i, 0), H - 1);
    f32x4 rowv = (f32x4)0.f;
#pragma unroll
    for (int j = 0; j < 3; ++j) {
      const int rx = min(max(mxi - 1 + j, 0), W - 1);
      rowv += wx[j] * *(const f32x4*)(pl + (size_t)(ry * W + rx) * 64);
    }
    acc += wy[i] * rowv;
  }
  *(f32x4*)(dst + ((size_t)b * OHW + opx) * 64 + chq * 4) = acc;
}

// ---------------- final 1x1 conv + clip ----------------
__global__ __launch_bounds__(256) void k_final(const float* __restrict__ outbuf,
                                               const float* __restrict__ out_w,
                                               const float* __restrict__ out_b,
                                               float* __restrict__ dout) {
  const int idx = blockIdx.x * 256 + threadIdx.x;
  const int b = idx >> 14, px = idx & 16383;
  const float* src = outbuf + ((size_t)b * 16384 + px) * 64;
  float a0 = out_b[0], a1 = out_b[1], a2 = out_b[2];
  for (int i = 0; i < 64; i += 4) {
    const f32x4 v = *(const f32x4*)(src + i);
    const f32x4 w0 = *(const f32x4*)(out_w + i);
    const f32x4 w1 = *(const f32x4*)(out_w + 64 + i);
    const f32x4 w2 = *(const f32x4*)(out_w + 128 + i);
#pragma unroll
    for (int e = 0; e < 4; ++e) {
      a0 = fmaf(w0[e], v[e], a0);
      a1 = fmaf(w1[e], v[e], a1);
      a2 = fmaf(w2[e], v[e], a2);
    }
  }
  const size_t base = (size_t)b * 49152 + px;
  dout[base] = fminf(fmaxf(a0, -1.f), 1.f);
  dout[base + 16384] = fminf(fmaxf(a1, -1.f), 1.f);
  dout[base + 32768] = fminf(fmaxf(a2, -1.f), 1.f);
  dout[393216 + base] = a0;
  dout[393216 + base + 16384] = a1;
  dout[393216 + base + 32768] = a2;
}

// ---------------- host launch ----------------
extern "C" void kernel_launch(void* const* d_in, const int* in_sizes, int n_in,
                              void* d_out, int out_size, void* d_ws, size_t ws_size,
                              hipStream_t stream) {
  const float* lat       = (const float*)d_in[0];
  const float* seed      = (const float*)d_in[1];
  const float* leak      = (const float*)d_in[2];
  const float* lat_exp_w = (const float*)d_in[3];
  const float* lat_exp_b = (const float*)d_in[4];
  const float* noise_w   = (const float*)d_in[5];
  const float* dyna_w    = (const float*)d_in[6];
  const float* dyna_b    = (const float*)d_in[7];
  const float* conv0_w   = (const float*)d_in[8];
  const float* conv0_b   = (const float*)d_in[9];
  const float* conv1_w   = (const float*)d_in[10];
  const float* conv1_b   = (const float*)d_in[11];
  const float* convs_w   = (const float*)d_in[12];
  const float* out_w     = (const float*)d_in[13];
  const float* out_b     = (const float*)d_in[14];

  float* wsf = (float*)d_ws;
  float* part = wsf + OFF_PART;
  float* b3   = wsf + OFF_B3;
  unsigned short* latc_bf = (unsigned short*)(wsf + OFF_LATCBF);
  float* out0 = wsf + OFF_OUT0;
  float* out1 = wsf + OFF_OUT1;
  unsigned short* wpk = (unsigned short*)(wsf + OFF_WPK);

  uint32_t lk0[NLAY_], lk1[NLAY_];
  for (int c = 0; c < NLAY_; ++c)
    host_tf_cipher(0u, 7u, 0u, (uint32_t)c, lk0[c], lk1[c]);

  const double ga = exp(-0.5);
  const float ge = (float)(ga / (1.0 + 2.0 * ga));
  const float gm = (float)(1.0 / (1.0 + 2.0 * ga));

  k_seed<<<(B_ * 256 * 64) / 256, 256, 0, stream>>>(seed, out0);
  k_latc<<<NLAY_, 256, 0, stream>>>(lat, lat_exp_w, lat_exp_b, latc_bf);
  k_wstatic<<<NLAY_ * B_, 256, 0, stream>>>(conv0_w, conv1_w, wpk);
  k_ks<<<P_ / 64, 256, 0, stream>>>(latc_bf, dyna_w, dyna_b, convs_w, wpk, b3);

  float* cur = out0;
  float* nxt = out1;
  int H = 16, W = 16, logW = 4;
  for (int c = 0; c < NLAY_; ++c) {
    const int HW = H * W;
    const int NS = (HW >= 16384) ? 32 : ((HW >= 4096) ? 16 : ((HW >= 1024) ? 8 : 4));
    k_stats1<<<dim3(NS, B_), 256, 0, stream>>>(cur, part, H, W, logW, HW, NS);
    k_main<<<dim3(HW / 64, B_), 256, 0, stream>>>(
        cur, nxt, part,
        wpk + (size_t)c * B_ * WPK_STRIDE, b3 + (size_t)c * B_ * 320,
        conv0_b, conv1_b, noise_w + c * F0_, leak,
        HW, W, logW - 4, NS, lk0[c], lk1[c]);
    { float* t = cur; cur = nxt; nxt = t; }
    if ((c & 3) == 3 && c < NLAY_ - 1) {
      const int n1 = B_ * 4 * HW * 16;
      const int loOW = logW + 1, loOHW = 2 * logW + 2;
      k_upgauss<<<(n1 + 255) / 256, 256, 0, stream>>>(cur, nxt, H, W, loOW, loOHW, ge, gm);
      { float* t = cur; cur = nxt; nxt = t; }
      H *= 2; W *= 2; logW += 1;
    }
  }
  k_final<<<(B_ * 16384) / 256, 256, 0, stream>>>(cur, out_w, out_b, (float*)d_out);
  (void)in_sizes; (void)n_in; (void)out_size; (void)ws_size;
}